// Round 12
// baseline (712.879 us; speedup 1.0000x reference)
//
#include <hip/hip_runtime.h>
#include <hip/hip_bf16.h>

typedef __attribute__((ext_vector_type(8))) __bf16 bx8;
typedef __attribute__((ext_vector_type(4))) float  fx4;

#define ROWS 8192   // B*S
#define HID  1024
#define MEMN 8192

// global_load_lds, 16B per lane; LDS dest = wave-uniform base + lane*16
#define GLDS(gp, lp) __builtin_amdgcn_global_load_lds( \
    (const __attribute__((address_space(1))) void*)(gp), \
    (__attribute__((address_space(3))) void*)(lp), 16, 0, 0)

#define MEMFENCE asm volatile("" ::: "memory")

// ---------------------------------------------------------------------------
// fp32 -> bf16 elementwise convert
// ---------------------------------------------------------------------------
__global__ __launch_bounds__(256)
void f32_to_bf16_vec(const float* __restrict__ in, __bf16* __restrict__ out)
{
    const size_t i = ((size_t)blockIdx.x * 256 + threadIdx.x) * 8;
    fx4 a = *(const fx4*)(in + i);
    fx4 b = *(const fx4*)(in + i + 4);
    bx8 u;
    u[0] = (__bf16)a[0]; u[1] = (__bf16)a[1]; u[2] = (__bf16)a[2]; u[3] = (__bf16)a[3];
    u[4] = (__bf16)b[0]; u[5] = (__bf16)b[1]; u[6] = (__bf16)b[2]; u[7] = (__bf16)b[3];
    *(bx8*)(out + i) = u;
}

// ---------------------------------------------------------------------------
// fp32 [R][C] -> bf16 [C][R] transpose (64x64 tiles via LDS).
// SCALE != nullptr: multiply element (r,c) by scale[r] (per input-row scale).
// ---------------------------------------------------------------------------
__global__ __launch_bounds__(256)
void transpose_f32_to_bf16(const float* __restrict__ in, __bf16* __restrict__ out,
                           const float* __restrict__ scale, int R, int C)
{
    __shared__ float t[64][65];
    const int tid = threadIdx.x;
    const int r0 = blockIdx.y * 64;
    const int c0 = blockIdx.x * 64;
    const int lr = tid >> 4;
    const int lc = (tid & 15) * 4;
#pragma unroll
    for (int p = 0; p < 4; ++p) {
        const int rr = p * 16 + lr;
        const fx4 v = *(const fx4*)(in + (size_t)(r0 + rr) * C + c0 + lc);
        t[rr][lc + 0] = v[0]; t[rr][lc + 1] = v[1];
        t[rr][lc + 2] = v[2]; t[rr][lc + 3] = v[3];
    }
    __syncthreads();
    const int oc = tid >> 2;
    const int ob = (tid & 3) * 16;
    bx8 u0, u1;
    if (scale) {
#pragma unroll
        for (int j = 0; j < 8; ++j) {
            u0[j] = (__bf16)(t[ob + j][oc]     * scale[r0 + ob + j]);
            u1[j] = (__bf16)(t[ob + 8 + j][oc] * scale[r0 + ob + 8 + j]);
        }
    } else {
#pragma unroll
        for (int j = 0; j < 8; ++j) {
            u0[j] = (__bf16)t[ob + j][oc];
            u1[j] = (__bf16)t[ob + 8 + j][oc];
        }
    }
    *(bx8*)(out + (size_t)(c0 + oc) * R + r0 + ob)     = u0;
    *(bx8*)(out + (size_t)(c0 + oc) * R + r0 + ob + 8) = u1;
}

// ---------------------------------------------------------------------------
// invert_rows: inv[r] = 1 / sum_{c<nchunk} part[c*8192 + r].  r < 8192.
// Consecutive threads read consecutive r -> coalesced per chunk.
// ---------------------------------------------------------------------------
__global__ __launch_bounds__(256)
void invert_rows(const float* __restrict__ part, float* __restrict__ inv,
                 int nchunk)
{
    const int r = blockIdx.x * 256 + threadIdx.x;
    float s = 0.f;
    for (int c = 0; c < nchunk; ++c) s += part[(size_t)c * 8192 + r];
    inv[r] = 1.0f / s;
}

// ---------------------------------------------------------------------------
// gemm8: round-3 verified NT GEMM core (ring-4 LDS, one counted vmcnt + one
// barrier per K-tile, PMC-verified conflict-free swizzle). Epilogue modes:
//   MODE 2: f32 out = c + add[idx]                        (write PV)
//   MODE 3: bf16 out = exp(c + bias[col]); per-row partial sums of exp
//           -> ((float*)add)[colchunk*8192 + row]         (read logits)
//   MODE 4: bf16 out = exp(c + bias[row]); per-col partial sums of exp
//           -> ((float*)add)[rowchunk*N + col]            (write logits -> W^T)
//   MODE 5: f32 out = c * bias[row]                       (read PV, 1/rowsum)
// Partial-sum coverage: each (chunk,index) is written by exactly one wave
// (no atomics, deterministic).
// ---------------------------------------------------------------------------
template <int BM, int BN, int MODE>
__global__ __launch_bounds__(512)
void gemm8(const __bf16* __restrict__ A, const __bf16* __restrict__ B,
           const float* __restrict__ bias, const float* __restrict__ add,
           void* __restrict__ out, int N, int K, int nBN)
{
    constexpr int ASZ = BM * 64;
    constexpr int BSZ = BN * 64;
    constexpr int RA  = BM / 128;
    constexpr int RB  = BN / 128;
    constexpr int L   = RA + RB;
    constexpr int RWM = BM / 2, RWN = BN / 4;
    constexpr int FM  = RWM / 16, FN = RWN / 16;

    __shared__ __align__(16) char smem[4 * (ASZ + BSZ)];

    const int tid = threadIdx.x;
    const int wid = tid >> 6;
    const int ln  = tid & 63;
    const int fl  = ln & 15;
    const int fh  = ln >> 4;
    const int wr  = wid >> 2;
    const int wc  = wid & 3;

    const int nwg = gridDim.x;
    const int bid = blockIdx.x;
    const int wg  = (bid & 7) * (nwg >> 3) + (bid >> 3);
    const int tm  = (wg / nBN) * BM;
    const int tn  = (wg % nBN) * BN;

    const int NT = K / 32;

    const __bf16* Ag[RA];
    const __bf16* Bg[RB];
#pragma unroll
    for (int R = 0; R < RA; ++R) {
        const int p = R * 512 + tid;
        Ag[R] = A + (size_t)(tm + (p >> 2)) * K + ((p & 3) ^ ((p >> 3) & 3)) * 8;
    }
#pragma unroll
    for (int R = 0; R < RB; ++R) {
        const int p = R * 512 + tid;
        Bg[R] = B + (size_t)(tn + (p >> 2)) * K + ((p & 3) ^ ((p >> 3) & 3)) * 8;
    }

    auto stage = [&](int t) {
        const int s = t & 3;
        const size_t ko = (size_t)t * 32;
        char* Ad = smem + s * ASZ + wid * 1024;
        char* Bd = smem + 4 * ASZ + s * BSZ + wid * 1024;
#pragma unroll
        for (int R = 0; R < RA; ++R) GLDS(Ag[R] + ko, Ad + R * 8192);
#pragma unroll
        for (int R = 0; R < RB; ++R) GLDS(Bg[R] + ko, Bd + R * 8192);
    };

    fx4 acc[FM][FN] = {};

    stage(0);
    if (NT > 1) stage(1);

    for (int t = 0; t < NT; ++t) {
        if (t == NT - 1) {
            asm volatile("s_waitcnt vmcnt(0)" ::: "memory");
        } else {
            asm volatile("s_waitcnt vmcnt(%0)" :: "i"(L) : "memory");
        }
        __builtin_amdgcn_s_barrier();
        MEMFENCE;
        if (t + 2 < NT) stage(t + 2);

        const char* Ab = smem + (t & 3) * ASZ;
        const char* Bb = smem + 4 * ASZ + (t & 3) * BSZ;
        bx8 fa[FM], fb[FN];
#pragma unroll
        for (int mi = 0; mi < FM; ++mi) {
            const int r = wr * RWM + mi * 16 + fl;
            fa[mi] = *(const bx8*)(Ab + r * 64 + ((fh ^ ((r >> 1) & 3)) << 4));
        }
#pragma unroll
        for (int ni = 0; ni < FN; ++ni) {
            const int c = wc * RWN + ni * 16 + fl;
            fb[ni] = *(const bx8*)(Bb + c * 64 + ((fh ^ ((c >> 1) & 3)) << 4));
        }
        __builtin_amdgcn_s_setprio(1);
#pragma unroll
        for (int mi = 0; mi < FM; ++mi)
#pragma unroll
            for (int ni = 0; ni < FN; ++ni)
                acc[mi][ni] = __builtin_amdgcn_mfma_f32_16x16x32_bf16(
                    fa[mi], fb[ni], acc[mi][ni], 0, 0, 0);
        __builtin_amdgcn_s_setprio(0);
    }

    // epilogue: C/D layout col = lane&15, row = (lane>>4)*4 + reg
    if constexpr (MODE == 3) {
        __bf16* O   = (__bf16*)out;
        float* part = (float*)add;                 // [128][8192]
        const int cc = (tn >> 6) + wc;             // column chunk (64 cols)
#pragma unroll
        for (int mi = 0; mi < FM; ++mi) {
            float ps[4] = {0.f, 0.f, 0.f, 0.f};
            const int gr0 = tm + wr * RWM + mi * 16 + fh * 4;
#pragma unroll
            for (int ni = 0; ni < FN; ++ni) {
                const int gc = tn + wc * RWN + ni * 16 + fl;
                const float bv = bias[gc];
                fx4 c = acc[mi][ni];
#pragma unroll
                for (int j = 0; j < 4; ++j) {
                    const float e = __expf(c[j] + bv);
                    O[(size_t)(gr0 + j) * N + gc] = (__bf16)e;
                    ps[j] += e;
                }
            }
#pragma unroll
            for (int j = 0; j < 4; ++j) {
#pragma unroll
                for (int off = 1; off <= 8; off <<= 1)
                    ps[j] += __shfl_xor(ps[j], off, 64);
                if (fl == 0)
                    part[(size_t)cc * 8192 + gr0 + j] = ps[j];
            }
        }
    } else if constexpr (MODE == 4) {
        __bf16* O    = (__bf16*)out;
        float* partc = (float*)add;                // [64][N]
        const int rc = (tm >> 7) + wr;             // row chunk (128 rows)
#pragma unroll
        for (int ni = 0; ni < FN; ++ni) {
            const int gc = tn + wc * RWN + ni * 16 + fl;
            float qs = 0.f;
#pragma unroll
            for (int mi = 0; mi < FM; ++mi) {
                const int gr0 = tm + wr * RWM + mi * 16 + fh * 4;
                fx4 c = acc[mi][ni];
#pragma unroll
                for (int j = 0; j < 4; ++j) {
                    const float e = __expf(c[j] + bias[gr0 + j]);
                    O[(size_t)(gr0 + j) * N + gc] = (__bf16)e;
                    qs += e;
                }
            }
            qs += __shfl_xor(qs, 16, 64);
            qs += __shfl_xor(qs, 32, 64);
            if (fh == 0)
                partc[(size_t)rc * N + gc] = qs;
        }
    } else {
#pragma unroll
        for (int mi = 0; mi < FM; ++mi) {
#pragma unroll
            for (int ni = 0; ni < FN; ++ni) {
                const int gr0 = tm + wr * RWM + mi * 16 + fh * 4;
                const int gc  = tn + wc * RWN + ni * 16 + fl;
                fx4 c = acc[mi][ni];
                if constexpr (MODE == 2) {
                    float* O = (float*)out;
#pragma unroll
                    for (int j = 0; j < 4; ++j) {
                        const size_t idx = (size_t)(gr0 + j) * N + gc;
                        O[idx] = c[j] + add[idx];
                    }
                } else {   // MODE 5
                    float* O = (float*)out;
#pragma unroll
                    for (int j = 0; j < 4; ++j)
                        O[(size_t)(gr0 + j) * N + gc] = c[j] * bias[gr0 + j];
                }
            }
        }
    }
}

// ---------------------------------------------------------------------------
// Orchestration. ws layout (176 MiB):
//   xb    [8192,1024] bf16  @ 0
//   slot1 @ 16 MiB : rwb then wwb
//   slot2 @ 32 MiB : memT, then xT*invc
//   W     @ 48 MiB : exp(read logits), then exp(write logits)^T (unnormalized)
// Reduction scratch lives in the out_mem half of d_out (dead until the final
// write-PV kernel):
//   part  [128][8192] f32 @ out_mem        (4 MB, read-logits row partials)
//   invr  [8192]      f32 @ out_mem+4MB
//   partc [64][8192]  f32 @ out_mem+4.5MB  (write-logits col partials)
//   invc  [8192]      f32 @ out_mem+6.5MB
// ---------------------------------------------------------------------------
extern "C" void kernel_launch(void* const* d_in, const int* in_sizes, int n_in,
                              void* d_out, int out_size, void* d_ws, size_t ws_size,
                              hipStream_t stream)
{
    const float* x       = (const float*)d_in[0];
    const float* memory  = (const float*)d_in[1];
    const float* read_w  = (const float*)d_in[2];
    const float* read_b  = (const float*)d_in[3];
    const float* write_w = (const float*)d_in[4];
    const float* write_b = (const float*)d_in[5];

    float* out_read = (float*)d_out;
    float* out_mem  = (float*)d_out + (size_t)MEMN * HID;

    char* p = (char*)d_ws;
    const size_t MiB = 1024 * 1024;
    __bf16* xb    = (__bf16*)(p + 0 * MiB);
    __bf16* slot1 = (__bf16*)(p + 16 * MiB);
    __bf16* slot2 = (__bf16*)(p + 32 * MiB);
    __bf16* W     = (__bf16*)(p + 48 * MiB);

    float* part  = out_mem;                        // 128*8192 floats
    float* invr  = out_mem + 128 * 8192;           // 8192 floats
    float* partc = invr + 8192;                    // 64*8192 floats
    float* invc  = partc + 64 * 8192;              // 8192 floats

    // ---- read path ---------------------------------------------------------
    f32_to_bf16_vec<<<4096, 256, 0, stream>>>(x, xb);
    f32_to_bf16_vec<<<4096, 256, 0, stream>>>(read_w, slot1);
    transpose_f32_to_bf16<<<dim3(HID / 64, ROWS / 64), 256, 0, stream>>>(
        memory, slot2, nullptr, ROWS, HID);
    // W[s][m] = exp(x.rw^T + rb), row partials -> part
    gemm8<256, 256, 3><<<(ROWS / 256) * (MEMN / 256), 512, 0, stream>>>(
        xb, slot1, read_b, part, W, MEMN, HID, MEMN / 256);
    invert_rows<<<32, 256, 0, stream>>>(part, invr, 128);
    // out_read[s][h] = invr[s] * sum_m W[s,m] mem[m,h]
    gemm8<128, 256, 5><<<(ROWS / 128) * (HID / 256), 512, 0, stream>>>(
        W, slot2, invr, nullptr, out_read, HID, MEMN, HID / 256);

    // ---- write path --------------------------------------------------------
    f32_to_bf16_vec<<<4096, 256, 0, stream>>>(write_w, slot1);
    // W^T[m][s] = exp(ww.x^T + wb[m]), col partials -> partc
    gemm8<256, 256, 4><<<(MEMN / 256) * (ROWS / 256), 512, 0, stream>>>(
        slot1, xb, write_b, partc, W, ROWS, HID, ROWS / 256);
    invert_rows<<<32, 256, 0, stream>>>(partc, invc, 64);
    // xT[h][s] = x[s][h] * invc[s]
    transpose_f32_to_bf16<<<dim3(HID / 64, ROWS / 64), 256, 0, stream>>>(
        x, slot2, invc, ROWS, HID);
    // out_mem[m][h] = memory[m,h] + sum_s W^T[m,s] * xT[h,s]
    gemm8<128, 256, 2><<<(MEMN / 128) * (HID / 256), 512, 0, stream>>>(
        W, slot2, nullptr, memory, out_mem, HID, ROWS, HID / 256);
}